// Round 1
// baseline (6517.222 us; speedup 1.0000x reference)
//
#include <hip/hip_runtime.h>
#include <math.h>

// MultiRNNCell: 2-layer LSTM-imputation scan.
// B=64, T=128, D=256, H=1024, gates G=4096.
// Key algebraic reductions:
//  - forget gate f is dead (cell state always 0): only i,g,o needed (3/4 of gate GEMM)
//  - layer1 uses h as both input and hx: fold W1 = Wih1+Whh1, b1 = bih1+bhh1
// Round-0 design: multi-launch (3 kernels per timestep), bf16 MFMA 16x16x32,
// fp32 accumulate + fp32 activations; weights converted to bf16 once per launch.

#define B_ 64
#define T_ 128
#define D_ 256
#define H_ 1024
#define G_ 4096

typedef __attribute__((ext_vector_type(8))) short short8;   // 8 bf16 = 4 VGPRs
typedef __attribute__((ext_vector_type(4))) float floatx4;  // MFMA C/D

__device__ __forceinline__ unsigned short f2bf(float x) {
    union { float f; unsigned u; } v; v.f = x;
    unsigned r = v.u + 0x7fffu + ((v.u >> 16) & 1u);  // RNE
    return (unsigned short)(r >> 16);
}
__device__ __forceinline__ float sigmoidf_(float x) { return 1.0f / (1.0f + expf(-x)); }

// ---------------- prep kernels (run once per launch) ----------------
__global__ void k_cvt(const float* __restrict__ s, unsigned short* __restrict__ d, int n) {
    int i = blockIdx.x * 256 + threadIdx.x;
    if (i < n) d[i] = f2bf(s[i]);
}
__global__ void k_addcvt(const float* __restrict__ a, const float* __restrict__ b,
                         unsigned short* __restrict__ d, int n) {
    int i = blockIdx.x * 256 + threadIdx.x;
    if (i < n) d[i] = f2bf(a[i] + b[i]);
}
__global__ void k_addf(const float* __restrict__ a, const float* __restrict__ b,
                       float* __restrict__ d, int n) {
    int i = blockIdx.x * 256 + threadIdx.x;
    if (i < n) d[i] = a[i] + b[i];
}
__global__ void k_zero(unsigned short* __restrict__ d, int n) {
    int i = blockIdx.x * 256 + threadIdx.x;
    if (i < n) d[i] = 0;
}

// ---------------- est + impute ----------------
// est[64x256] = hbf[64x1024] @ Woutbf[256x1024]^T + bout
// imputed = m*x + (1-m)*est  (skipped when t==T, i.e. the final projection)
// est written to out[:, t-1, :] for t>=1.
// grid = 16 blocks (n-tile), block = 256 = 4 waves (m-tile per wave).
__global__ __launch_bounds__(256) void k_est(
    const unsigned short* __restrict__ hbf, const unsigned short* __restrict__ Woutbf,
    const float* __restrict__ bout, const float* __restrict__ X, const float* __restrict__ Mm,
    unsigned short* __restrict__ impbf, float* __restrict__ out, int t)
{
    int lane = threadIdx.x & 63;
    int mt   = threadIdx.x >> 6;     // wave id = m-tile
    int nt   = blockIdx.x;           // n-tile (d columns)
    int r16  = lane & 15, quad = lane >> 4;

    const unsigned short* aP = hbf    + (mt * 16 + r16) * H_ + quad * 8;  // A[m][k]
    const unsigned short* bP = Woutbf + (nt * 16 + r16) * H_ + quad * 8;  // B[k][n] = W[n][k]
    floatx4 acc = {0.f, 0.f, 0.f, 0.f};
    #pragma unroll 4
    for (int k = 0; k < H_; k += 32) {
        short8 a = *(const short8*)(aP + k);
        short8 b = *(const short8*)(bP + k);
        acc = __builtin_amdgcn_mfma_f32_16x16x32_bf16(a, b, acc, 0, 0, 0);
    }
    int dd = nt * 16 + r16;          // C col = lane&15 -> d index
    float bo = bout[dd];
    #pragma unroll
    for (int r = 0; r < 4; r++) {
        int bb = mt * 16 + quad * 4 + r;   // C row = quad*4+reg -> b index
        float est = acc[r] + bo;
        if (t < T_) {
            float x = X [(bb * T_ + t) * D_ + dd];
            float m = Mm[(bb * T_ + t) * D_ + dd];
            impbf[bb * D_ + dd] = f2bf(m * x + (1.0f - m) * est);
        }
        if (t >= 1) out[(bb * T_ + (t - 1)) * D_ + dd] = est;
    }
}

// ---------------- LSTM layer (i,g,o gates only) ----------------
// gates[b][n] over A-segments: seg1 A1[64xK1] w/ W1 rows (stride K1),
// optional seg2 A2[64xK2] w/ W2 rows. Gate rows: i at n, g at 2H+n, o at 3H+n.
// h = sigmoid(o) * tanh( sigmoid(i) * tanh(g) )
// grid = 64 blocks (n-tile of 16 units), block = 256 = 4 waves (m-tiles).
__global__ __launch_bounds__(256) void k_lstm(
    const unsigned short* __restrict__ A1, int K1, const unsigned short* __restrict__ W1,
    const unsigned short* __restrict__ A2, int K2, const unsigned short* __restrict__ W2,
    const float* __restrict__ bias,
    unsigned short* __restrict__ hout_bf, float* __restrict__ hout_f32)
{
    int lane = threadIdx.x & 63;
    int mt   = threadIdx.x >> 6;
    int nt   = blockIdx.x;
    int r16  = lane & 15, quad = lane >> 4;

    floatx4 ai = {0.f,0.f,0.f,0.f}, ag = {0.f,0.f,0.f,0.f}, ao = {0.f,0.f,0.f,0.f};

    {   // segment 1
        const unsigned short* aP = A1 + (mt * 16 + r16) * K1 + quad * 8;
        const unsigned short* wi = W1 + (          nt * 16 + r16) * K1 + quad * 8;
        const unsigned short* wg = W1 + (2 * H_ + nt * 16 + r16) * K1 + quad * 8;
        const unsigned short* wo = W1 + (3 * H_ + nt * 16 + r16) * K1 + quad * 8;
        for (int k = 0; k < K1; k += 32) {
            short8 a = *(const short8*)(aP + k);
            ai = __builtin_amdgcn_mfma_f32_16x16x32_bf16(a, *(const short8*)(wi + k), ai, 0, 0, 0);
            ag = __builtin_amdgcn_mfma_f32_16x16x32_bf16(a, *(const short8*)(wg + k), ag, 0, 0, 0);
            ao = __builtin_amdgcn_mfma_f32_16x16x32_bf16(a, *(const short8*)(wo + k), ao, 0, 0, 0);
        }
    }
    if (K2 > 0) {   // segment 2
        const unsigned short* aP = A2 + (mt * 16 + r16) * K2 + quad * 8;
        const unsigned short* wi = W2 + (          nt * 16 + r16) * K2 + quad * 8;
        const unsigned short* wg = W2 + (2 * H_ + nt * 16 + r16) * K2 + quad * 8;
        const unsigned short* wo = W2 + (3 * H_ + nt * 16 + r16) * K2 + quad * 8;
        for (int k = 0; k < K2; k += 32) {
            short8 a = *(const short8*)(aP + k);
            ai = __builtin_amdgcn_mfma_f32_16x16x32_bf16(a, *(const short8*)(wi + k), ai, 0, 0, 0);
            ag = __builtin_amdgcn_mfma_f32_16x16x32_bf16(a, *(const short8*)(wg + k), ag, 0, 0, 0);
            ao = __builtin_amdgcn_mfma_f32_16x16x32_bf16(a, *(const short8*)(wo + k), ao, 0, 0, 0);
        }
    }

    int n = nt * 16 + r16;           // C col -> unit index
    float bi = bias[n], bg = bias[2 * H_ + n], bo = bias[3 * H_ + n];
    #pragma unroll
    for (int r = 0; r < 4; r++) {
        int bb = mt * 16 + quad * 4 + r;   // C row -> b index
        float i_ = ai[r] + bi;
        float g_ = ag[r] + bg;
        float o_ = ao[r] + bo;
        float c  = sigmoidf_(i_) * tanhf(g_);
        float h  = sigmoidf_(o_) * tanhf(c);
        hout_bf[bb * H_ + n] = f2bf(h);
        if (hout_f32) hout_f32[bb * H_ + n] = h;
    }
}

extern "C" void kernel_launch(void* const* d_in, const int* in_sizes, int n_in,
                              void* d_out, int out_size, void* d_ws, size_t ws_size,
                              hipStream_t stream) {
    const float* X    = (const float*)d_in[0];
    const float* Mm   = (const float*)d_in[1];
    const float* Wih0 = (const float*)d_in[2];
    const float* Whh0 = (const float*)d_in[3];
    const float* bih0 = (const float*)d_in[4];
    const float* bhh0 = (const float*)d_in[5];
    const float* Wih1 = (const float*)d_in[6];
    const float* Whh1 = (const float*)d_in[7];
    const float* bih1 = (const float*)d_in[8];
    const float* bhh1 = (const float*)d_in[9];
    const float* Wout = (const float*)d_in[10];
    const float* bout = (const float*)d_in[11];
    float* out = (float*)d_out;

    // workspace carve-up (256B aligned)
    char* ws = (char*)d_ws;
    size_t off = 0;
    auto alloc = [&](size_t bytes) { char* p = ws + off; off = (off + bytes + 255) & ~(size_t)255; return p; };
    unsigned short* hbf    = (unsigned short*)alloc(B_ * H_ * 2);
    unsigned short* h0bf   = (unsigned short*)alloc(B_ * H_ * 2);
    unsigned short* impbf  = (unsigned short*)alloc(B_ * D_ * 2);
    unsigned short* Wih0bf = (unsigned short*)alloc((size_t)G_ * D_ * 2);
    unsigned short* Whh0bf = (unsigned short*)alloc((size_t)G_ * H_ * 2);
    unsigned short* W1bf   = (unsigned short*)alloc((size_t)G_ * H_ * 2);
    unsigned short* Woutbf = (unsigned short*)alloc((size_t)D_ * H_ * 2);
    float*          b0c    = (float*)alloc(G_ * 4);
    float*          b1c    = (float*)alloc(G_ * 4);

    // prep: weight conversions + bias folds + h=0
    {
        int n;
        n = G_ * D_; k_cvt   <<<(n + 255) / 256, 256, 0, stream>>>(Wih0, Wih0bf, n);
        n = G_ * H_; k_cvt   <<<(n + 255) / 256, 256, 0, stream>>>(Whh0, Whh0bf, n);
        n = G_ * H_; k_addcvt<<<(n + 255) / 256, 256, 0, stream>>>(Wih1, Whh1, W1bf, n);
        n = D_ * H_; k_cvt   <<<(n + 255) / 256, 256, 0, stream>>>(Wout, Woutbf, n);
        n = G_;      k_addf  <<<(n + 255) / 256, 256, 0, stream>>>(bih0, bhh0, b0c, n);
        n = G_;      k_addf  <<<(n + 255) / 256, 256, 0, stream>>>(bih1, bhh1, b1c, n);
        n = B_ * H_; k_zero  <<<(n + 255) / 256, 256, 0, stream>>>(hbf, n);
    }

    float* out_hfinal = out + (size_t)B_ * T_ * D_;

    for (int t = 0; t < T_; ++t) {
        k_est <<<16, 256, 0, stream>>>(hbf, Woutbf, bout, X, Mm, impbf, out, t);
        k_lstm<<<64, 256, 0, stream>>>(impbf, D_, Wih0bf, hbf, H_, Whh0bf, b0c, h0bf, nullptr);
        k_lstm<<<64, 256, 0, stream>>>(h0bf, H_, W1bf, nullptr, 0, nullptr, b1c, hbf,
                                       (t == T_ - 1) ? out_hfinal : nullptr);
    }
    // final projection: est from h(T-1) -> out[:, T-1, :]
    k_est<<<16, 256, 0, stream>>>(hbf, Woutbf, bout, X, Mm, impbf, out, T_);
}